// Round 8
// baseline (224.307 us; speedup 1.0000x reference)
//
#include <hip/hip_runtime.h>
#include <math.h>

// b=4,n=2048 -> 8192 rows; d=1024; h=8; e=16; cs=2048. Output int32 [8192,8].
// argmax_c q.cbn_c == argmax_c ((x.W - mu*colsum(W)) . cbn_c): LN 1/sigma and
// q-norm are positive per-(row,head) scalars -> cancel. Codebook normalized fp64.
//
// MFMA path: fp32 operands split into 3 bf16 parts h,m,l (8+8+8 >= 24 mantissa
// bits; bf16 exponent = fp32 -> no subnormal flush). v_p*v_c ~= hh + hm+mh +
// hl+mm+lh via 3 K=32 bf16 MFMAs with quad-packing: quads 0,1 carry part-A of
// the pair, quads 2,3 part-B. Dropped ml/lm/ll ~2^-25 rel.

typedef short bf16x8 __attribute__((ext_vector_type(8)));
typedef float f32x4 __attribute__((ext_vector_type(4)));

__device__ __forceinline__ unsigned short f2bf(float f) {
  unsigned u = __builtin_bit_cast(unsigned, f);
  unsigned r = (u + 0x7FFFu + ((u >> 16) & 1u)) >> 16;   // RNE
  return (unsigned short)r;
}
__device__ __forceinline__ float bf2f(unsigned short b) {
  return __builtin_bit_cast(float, (unsigned)b << 16);
}
__device__ __forceinline__ void split3(float v, unsigned short& h,
                                       unsigned short& m, unsigned short& l) {
  h = f2bf(v);
  float r = v - bf2f(h);
  m = f2bf(r);
  float r2 = r - bf2f(m);
  l = f2bf(r2);
}

// ---------------- K1: normalize codebook (fp64) + bf16 3-split --------------
__global__ __launch_bounds__(256) void k_cbnorm(const float* __restrict__ cb,
                                                unsigned short* __restrict__ ch,
                                                unsigned short* __restrict__ cm,
                                                unsigned short* __restrict__ cl) {
  int v = blockIdx.x * 256 + threadIdx.x;      // 0..16383 code vectors
  const float4* p = (const float4*)(cb + (size_t)v * 16);
  float4 q0 = p[0], q1 = p[1], q2 = p[2], q3 = p[3];
  float f[16] = {q0.x,q0.y,q0.z,q0.w, q1.x,q1.y,q1.z,q1.w,
                 q2.x,q2.y,q2.z,q2.w, q3.x,q3.y,q3.z,q3.w};
  double s = 0.0;
#pragma unroll
  for (int i = 0; i < 16; ++i) s += (double)f[i] * (double)f[i];
  double inv = 1.0 / sqrt(s + 1e-12);
  unsigned short vh[16], vm[16], vl[16];
#pragma unroll
  for (int i = 0; i < 16; ++i)
    split3((float)((double)f[i] * inv), vh[i], vm[i], vl[i]);
#pragma unroll
  for (int i = 0; i < 2; ++i) {
    ((bf16x8*)(ch + (size_t)v * 16))[i] = ((bf16x8*)vh)[i];
    ((bf16x8*)(cm + (size_t)v * 16))[i] = ((bf16x8*)vm)[i];
    ((bf16x8*)(cl + (size_t)v * 16))[i] = ((bf16x8*)vl)[i];
  }
}

// ---------------- K2: column sums of W --------------------------------------
__global__ __launch_bounds__(256) void k_colsum(const float* __restrict__ W,
                                                float* __restrict__ cs) {
  __shared__ float red[16][17];
  int h = blockIdx.x;
  int e = threadIdx.x & 15, part = threadIdx.x >> 4;
  const float* base = W + h * 16384 + e;
  float s = 0.f;
  int d0 = part * 64;
  for (int i = 0; i < 64; ++i) s += base[(d0 + i) * 16];
  red[e][part] = s;
  __syncthreads();
  if (threadIdx.x < 16) {
    float t = 0.f;
#pragma unroll
    for (int p = 0; p < 16; ++p) t += red[threadIdx.x][p];
    cs[h * 16 + threadIdx.x] = t;
  }
}

// ---------------- K2b: W transpose + bf16 3-split ---------------------------
__global__ __launch_bounds__(256) void k_wsplit(const float* __restrict__ W,
                                                unsigned short* __restrict__ Wth,
                                                unsigned short* __restrict__ Wtm,
                                                unsigned short* __restrict__ Wtl) {
  int idx = blockIdx.x * 256 + threadIdx.x;    // 0..131071
  int d = idx & 1023, col = idx >> 10;
  int h = col >> 4, e = col & 15;
  float v = W[h * 16384 + d * 16 + e];
  unsigned short a, b, c;
  split3(v, a, b, c);
  Wth[(size_t)col * 1024 + d] = a;
  Wtm[(size_t)col * 1024 + d] = b;
  Wtl[(size_t)col * 1024 + d] = c;
}

// ---------------- K2c: row means of x ---------------------------------------
__global__ __launch_bounds__(256) void k_mu(const float* __restrict__ x,
                                            float* __restrict__ mu) {
  __shared__ float red[16][17];
  const int t = threadIdx.x;
  const int g = t & 15, tg = t >> 4;
  const int row = blockIdx.x * 16 + tg;
  const float4* xr = (const float4*)(x + (size_t)row * 1024);
  float s = 0.f;
#pragma unroll
  for (int m = 0; m < 16; ++m) {
    float4 v = xr[g + 16 * m];
    s += (v.x + v.y) + (v.z + v.w);
  }
  red[tg][g] = s;
  __syncthreads();
  if (g == 0) {
    float tt = 0.f;
#pragma unroll
    for (int k = 0; k < 16; ++k) tt += red[tg][k];
    mu[row] = tt * (1.0f / 1024.0f);
  }
}

// ---------------- K3: projection GEMM, LDS-free MFMA ------------------------
// Grid (128 rowgroups, 8 ks) x 256 = 1024 blocks (4/CU). Block: 64 rows x
// 128 cols x K=128 d (8 d-groups of 16). Wave = 16 rows (one M-tile).
// Per d-group: lane loads 8 fp32 x's (row = n16) -> split3 in-register ->
// A1=(q<2?h:m), A3=(q<2?h:l); B direct from W-split arrays (L2-resident,
// reused by all 128 rowgroups). 24 MFMAs per d-group per wave. No LDS.
__global__ __launch_bounds__(256) void k_proj(const float* __restrict__ x,
                                              const unsigned short* __restrict__ Wth,
                                              const unsigned short* __restrict__ Wtm,
                                              const unsigned short* __restrict__ Wtl,
                                              float* __restrict__ part) {
  const int t = threadIdx.x;
  const int lane = t & 63, w = t >> 6;
  const int r0 = blockIdx.x * 64;
  const int ks = blockIdx.y;
  const int q = lane >> 4, n16 = lane & 15;
  const bool qlt2 = (q < 2);
  const int row = r0 + w * 16 + n16;

  const unsigned short* pb1 = qlt2 ? Wth : Wtm;
  const unsigned short* pb2 = qlt2 ? Wtm : Wth;
  const unsigned short* pb3 = qlt2 ? Wtl : Wth;

  f32x4 acc[8];
#pragma unroll
  for (int h = 0; h < 8; ++h) acc[h] = (f32x4){0.f, 0.f, 0.f, 0.f};

  for (int dg = 0; dg < 8; ++dg) {
    const int dq = ks * 128 + dg * 16 + (q & 1) * 8;
    float4 xa = *(const float4*)(x + (size_t)row * 1024 + dq);
    float4 xb = *(const float4*)(x + (size_t)row * 1024 + dq + 4);
    float xf[8] = {xa.x, xa.y, xa.z, xa.w, xb.x, xb.y, xb.z, xb.w};
    unsigned short s1[8], s3[8];
#pragma unroll
    for (int j = 0; j < 8; ++j) {
      unsigned short hh, mm, ll;
      split3(xf[j], hh, mm, ll);
      s1[j] = qlt2 ? hh : mm;
      s3[j] = qlt2 ? hh : ll;
    }
    bf16x8 a1 = *(bf16x8*)s1;
    bf16x8 a3 = *(bf16x8*)s3;
#pragma unroll
    for (int h = 0; h < 8; ++h) {
      size_t wo = (size_t)(h * 16 + n16) * 1024 + dq;
      bf16x8 b1 = *(const bf16x8*)(pb1 + wo);
      bf16x8 b2 = *(const bf16x8*)(pb2 + wo);
      bf16x8 b3 = *(const bf16x8*)(pb3 + wo);
      acc[h] = __builtin_amdgcn_mfma_f32_16x16x32_bf16(a1, b1, acc[h], 0, 0, 0);
      acc[h] = __builtin_amdgcn_mfma_f32_16x16x32_bf16(a1, b2, acc[h], 0, 0, 0);
      acc[h] = __builtin_amdgcn_mfma_f32_16x16x32_bf16(a3, b3, acc[h], 0, 0, 0);
    }
  }

  float* po = part + ((size_t)ks * 8192 + r0 + w * 16) * 128;
#pragma unroll
  for (int h = 0; h < 8; ++h)
#pragma unroll
    for (int r = 0; r < 4; ++r)
      po[(size_t)(q * 4 + r) * 128 + h * 16 + n16] = acc[h][r];
}

// ---------------- K3b: combine 8 K-slices - mu*colsum, emit bf16 splits -----
__global__ __launch_bounds__(256) void k_combine(const float* __restrict__ part,
                                                 const float* __restrict__ mu,
                                                 const float* __restrict__ csum,
                                                 unsigned short* __restrict__ ph,
                                                 unsigned short* __restrict__ pm,
                                                 unsigned short* __restrict__ pl) {
  int idx = blockIdx.x * 256 + threadIdx.x;   // f4 index, 262144 total
  int row = idx >> 5, c4 = (idx & 31) * 4;
  float4 a = {0.f, 0.f, 0.f, 0.f};
#pragma unroll
  for (int s = 0; s < 8; ++s) {
    float4 p = *(const float4*)(part + ((size_t)s * 8192 + row) * 128 + c4);
    a.x += p.x; a.y += p.y; a.z += p.z; a.w += p.w;
  }
  float4 cs = *(const float4*)(csum + c4);
  float m = mu[row];
  float o[4] = {a.x - m * cs.x, a.y - m * cs.y, a.z - m * cs.z, a.w - m * cs.w};
  unsigned short vh[4], vm[4], vl[4];
#pragma unroll
  for (int k = 0; k < 4; ++k) split3(o[k], vh[k], vm[k], vl[k]);
  int head = c4 >> 4, e0 = c4 & 15;
  size_t base = ((size_t)head * 8192 + row) * 16 + e0;
  *(short4*)(ph + base) = *(short4*)vh;
  *(short4*)(pm + base) = *(short4*)vm;
  *(short4*)(pl + base) = *(short4*)vl;
}

// ---------------- K4: MFMA argmax partials (bf16 splits, prefetched) --------
// Grid (32 rowgroups, 8 heads, 8 code-eighths) x 256 = 2048 blocks (8/CU).
// Wave = 64 rows (4 row-tiles, A-frags in regs, reused over 16 code-tiles).
// B-frags for tile+1 prefetched into regs while tile's MFMAs run. Per-lane
// codes ascend -> strict '>' = first max; cross-lane shfl_xor(w16)
// lexicographic; eighths merged in k_amred.
__global__ __launch_bounds__(256) void k_argmax(
    const unsigned short* __restrict__ ph, const unsigned short* __restrict__ pm,
    const unsigned short* __restrict__ pl, const unsigned short* __restrict__ ch,
    const unsigned short* __restrict__ cm, const unsigned short* __restrict__ cl,
    float* __restrict__ amv, int* __restrict__ ami) {
  const int t = threadIdx.x;
  const int lane = t & 63, w = t >> 6;
  const int h = blockIdx.y;
  const int z = blockIdx.z;
  const int r0 = blockIdx.x * 256 + w * 64;
  const int q = lane >> 4;
  const int n16 = lane & 15;
  const int ehalf = (q & 1) * 8;
  const bool qlt2 = (q < 2);

  const unsigned short* pa1 = qlt2 ? ph : pm;   // A1 = [h|m]
  const unsigned short* pa3 = qlt2 ? ph : pl;   // A3 = [h|l]
  bf16x8 a1[4], a3[4];
#pragma unroll
  for (int rt = 0; rt < 4; ++rt) {
    size_t off = ((size_t)h * 8192 + r0 + rt * 16 + n16) * 16 + ehalf;
    a1[rt] = *(const bf16x8*)(pa1 + off);
    a3[rt] = *(const bf16x8*)(pa3 + off);
  }

  float best[4][4];
  int   bidx[4][4];
#pragma unroll
  for (int rt = 0; rt < 4; ++rt)
#pragma unroll
    for (int r = 0; r < 4; ++r) { best[rt][r] = -3.402823466e38f; bidx[rt][r] = 0; }

  const unsigned short* pb1 = qlt2 ? ch : cm;   // B1 = [h|m]
  const unsigned short* pb2 = qlt2 ? cm : ch;   // B2 = [m|h]
  const unsigned short* pb3 = qlt2 ? cl : ch;   // B3 = [l|h]
  const size_t cbase = ((size_t)h * 2048 + z * 256) * 16;

  size_t off0 = cbase + (size_t)n16 * 16 + ehalf;
  bf16x8 b1 = *(const bf16x8*)(pb1 + off0);
  bf16x8 b2 = *(const bf16x8*)(pb2 + off0);
  bf16x8 b3 = *(const bf16x8*)(pb3 + off0);

  for (int tile = 0; tile < 16; ++tile) {
    bf16x8 nb1, nb2, nb3;
    if (tile < 15) {   // prefetch next tile's B while this tile computes
      size_t noff = cbase + (size_t)((tile + 1) * 16 + n16) * 16 + ehalf;
      nb1 = *(const bf16x8*)(pb1 + noff);
      nb2 = *(const bf16x8*)(pb2 + noff);
      nb3 = *(const bf16x8*)(pb3 + noff);
    }
    const int code = z * 256 + tile * 16 + n16;
#pragma unroll
    for (int rt = 0; rt < 4; ++rt) {
      f32x4 acc = {0.f, 0.f, 0.f, 0.f};
      acc = __builtin_amdgcn_mfma_f32_16x16x32_bf16(a1[rt], b1, acc, 0, 0, 0);
      acc = __builtin_amdgcn_mfma_f32_16x16x32_bf16(a1[rt], b2, acc, 0, 0, 0);
      acc = __builtin_amdgcn_mfma_f32_16x16x32_bf16(a3[rt], b3, acc, 0, 0, 0);
#pragma unroll
      for (int r = 0; r < 4; ++r)
        if (acc[r] > best[rt][r]) { best[rt][r] = acc[r]; bidx[rt][r] = code; }
    }
    b1 = nb1; b2 = nb2; b3 = nb3;
  }

#pragma unroll
  for (int off = 8; off >= 1; off >>= 1) {
#pragma unroll
    for (int rt = 0; rt < 4; ++rt)
#pragma unroll
      for (int r = 0; r < 4; ++r) {
        float ov = __shfl_xor(best[rt][r], off, 16);
        int   oi = __shfl_xor(bidx[rt][r], off, 16);
        if (ov > best[rt][r] || (ov == best[rt][r] && oi < bidx[rt][r])) {
          best[rt][r] = ov; bidx[rt][r] = oi;
        }
      }
  }
  if (n16 == 0) {
#pragma unroll
    for (int rt = 0; rt < 4; ++rt)
#pragma unroll
      for (int r = 0; r < 4; ++r) {
        int row = r0 + rt * 16 + q * 4 + r;
        size_t o = (size_t)z * 65536 + (size_t)row * 8 + h;
        amv[o] = best[rt][r]; ami[o] = bidx[rt][r];
      }
  }
}

// ---------------- K5: merge the eight code-eighths --------------------------
__global__ __launch_bounds__(256) void k_amred(const float* __restrict__ amv,
                                               const int* __restrict__ ami,
                                               int* __restrict__ out) {
  int i = blockIdx.x * 256 + threadIdx.x;   // 65536
  float bv = amv[i]; int bi = ami[i];
#pragma unroll
  for (int z = 1; z < 8; ++z) {
    float v = amv[(size_t)z * 65536 + i];
    if (v > bv) { bv = v; bi = ami[(size_t)z * 65536 + i]; }
  }
  out[i] = bi;
}

extern "C" void kernel_launch(void* const* d_in, const int* in_sizes, int n_in,
                              void* d_out, int out_size, void* d_ws, size_t ws_size,
                              hipStream_t stream) {
  (void)in_sizes; (void)n_in; (void)out_size; (void)ws_size;
  const float* x  = (const float*)d_in[0];   // [4,2048,1024]
  const float* rp = (const float*)d_in[1];   // [8,1024,16]
  const float* cb = (const float*)d_in[2];   // [8,2048,16]
  int* out = (int*)d_out;                    // [8192,8] int32

  float* ws = (float*)d_ws;
  float*          csum = ws;                               // 128
  float*          mu   = ws + 128;                         // 8192
  float*          part = ws + 8320;                        // 8*8192*128
  unsigned short* Wth  = (unsigned short*)(ws + 8396928);  // 131072 sh each
  unsigned short* Wtm  = (unsigned short*)(ws + 8462464);
  unsigned short* Wtl  = (unsigned short*)(ws + 8528000);
  unsigned short* ch   = (unsigned short*)(ws + 8593536);  // 262144 sh each
  unsigned short* cm   = (unsigned short*)(ws + 8724608);
  unsigned short* cl   = (unsigned short*)(ws + 8855680);
  unsigned short* ph   = (unsigned short*)(ws + 8986752);  // 1048576 sh each
  unsigned short* pm   = (unsigned short*)(ws + 9511040);
  unsigned short* pl   = (unsigned short*)(ws + 10035328);
  float*          amv  = ws + 10559616;                    // 524288
  int*            ami  = (int*)(ws + 11083904);            // 524288 (~46.4 MB)

  hipLaunchKernelGGL(k_cbnorm,  dim3(64),        dim3(256), 0, stream, cb, ch, cm, cl);
  hipLaunchKernelGGL(k_colsum,  dim3(8),         dim3(256), 0, stream, rp, csum);
  hipLaunchKernelGGL(k_wsplit,  dim3(512),       dim3(256), 0, stream, rp, Wth, Wtm, Wtl);
  hipLaunchKernelGGL(k_mu,      dim3(512),       dim3(256), 0, stream, x, mu);
  hipLaunchKernelGGL(k_proj,    dim3(128, 8),    dim3(256), 0, stream, x, Wth, Wtm, Wtl, part);
  hipLaunchKernelGGL(k_combine, dim3(1024),      dim3(256), 0, stream, part, mu, csum, ph, pm, pl);
  hipLaunchKernelGGL(k_argmax,  dim3(32, 8, 8),  dim3(256), 0, stream, ph, pm, pl, ch, cm, cl, amv, ami);
  hipLaunchKernelGGL(k_amred,   dim3(256),       dim3(256), 0, stream, amv, ami, out);
}

// Round 10
// 162.597 us; speedup vs baseline: 1.3795x; 1.3795x over previous
//
#include <hip/hip_runtime.h>
#include <math.h>

// b=4,n=2048 -> 8192 rows; d=1024; h=8; e=16; cs=2048. Output int32 [8192,8].
// argmax_c q.cbn_c == argmax_c ((x.W - mu*colsum(W)) . cbn_c): LN 1/sigma and
// q-norm are positive per-(row,head) scalars -> cancel. Codebook normalized fp64.
//
// MFMA path (verified R7/R8): fp32 operands split into 3 bf16 parts h,m,l
// (8+8+8 >= 24 mantissa bits; bf16 exp = fp32 -> no subnormal flush).
// v_p*v_c ~= hh + hm+mh + hl+mm+lh via 3 K=32 bf16 MFMAs, quad-packed:
// quads 0,1 carry part-A of the pair, quads 2,3 part-B. Dropped ml/lm/ll
// ~2^-25 rel.
//
// R9: fragment-major pre-swizzled B layouts (1 dense 1KB region per wave
// B-load instead of 32 scattered segments -> kills TA serialization).
// R10: fix wfrag consumer index: global d-group = ks*8+dg (R9 used local dg).

typedef short bf16x8 __attribute__((ext_vector_type(8)));
typedef float f32x4 __attribute__((ext_vector_type(4)));

__device__ __forceinline__ unsigned short f2bf(float f) {
  unsigned u = __builtin_bit_cast(unsigned, f);
  unsigned r = (u + 0x7FFFu + ((u >> 16) & 1u)) >> 16;   // RNE
  return (unsigned short)r;
}
__device__ __forceinline__ float bf2f(unsigned short b) {
  return __builtin_bit_cast(float, (unsigned)b << 16);
}
__device__ __forceinline__ void split3(float v, unsigned short& h,
                                       unsigned short& m, unsigned short& l) {
  h = f2bf(v);
  float r = v - bf2f(h);
  m = f2bf(r);
  float r2 = r - bf2f(m);
  l = f2bf(r2);
}

// ---------------- K1: normalize codebook (fp64) -> frag-major cfrag ---------
// cfrag layout: [h(8)][tile(128)][p(3)][n(16)][oct(2)][j(8)] shorts (1.5 MB).
__global__ __launch_bounds__(256) void k_cbnorm(const float* __restrict__ cb,
                                                unsigned short* __restrict__ cfrag) {
  int v = blockIdx.x * 256 + threadIdx.x;      // 0..16383 code vectors
  int h = v >> 11, c = v & 2047, tl = c >> 4, n = c & 15;
  const float4* p = (const float4*)(cb + (size_t)v * 16);
  float4 q0 = p[0], q1 = p[1], q2 = p[2], q3 = p[3];
  float f[16] = {q0.x,q0.y,q0.z,q0.w, q1.x,q1.y,q1.z,q1.w,
                 q2.x,q2.y,q2.z,q2.w, q3.x,q3.y,q3.z,q3.w};
  double s = 0.0;
#pragma unroll
  for (int i = 0; i < 16; ++i) s += (double)f[i] * (double)f[i];
  double inv = 1.0 / sqrt(s + 1e-12);
  __attribute__((aligned(16))) unsigned short vp[3][16];
#pragma unroll
  for (int i = 0; i < 16; ++i)
    split3((float)((double)f[i] * inv), vp[0][i], vp[1][i], vp[2][i]);
#pragma unroll
  for (int pp = 0; pp < 3; ++pp) {
    size_t base = ((((size_t)h * 128 + tl) * 3 + pp) * 16 + n) * 16;
    ((bf16x8*)(cfrag + base))[0] = ((bf16x8*)vp[pp])[0];
    ((bf16x8*)(cfrag + base))[1] = ((bf16x8*)vp[pp])[1];
  }
}

// ---------------- K2: column sums of W --------------------------------------
__global__ __launch_bounds__(256) void k_colsum(const float* __restrict__ W,
                                                float* __restrict__ cs) {
  __shared__ float red[16][17];
  int h = blockIdx.x;
  int e = threadIdx.x & 15, part = threadIdx.x >> 4;
  const float* base = W + h * 16384 + e;
  float s = 0.f;
  int d0 = part * 64;
  for (int i = 0; i < 64; ++i) s += base[(d0 + i) * 16];
  red[e][part] = s;
  __syncthreads();
  if (threadIdx.x < 16) {
    float t = 0.f;
#pragma unroll
    for (int p = 0; p < 16; ++p) t += red[threadIdx.x][p];
    cs[h * 16 + threadIdx.x] = t;
  }
}

// ---------------- K2b: W -> frag-major bf16-split wfrag ---------------------
// wfrag layout: [dg(64)][c=head(8)][p(3)][n=e(16)][oct(2)][j(8)] (768 KB).
__global__ __launch_bounds__(256) void k_wsplit(const float* __restrict__ W,
                                                unsigned short* __restrict__ wfrag) {
  int id = blockIdx.x * 256 + threadIdx.x;     // 0..16383
  int o = id & 1, n = (id >> 1) & 15, c = (id >> 5) & 7, dg = id >> 8;
  __attribute__((aligned(16))) unsigned short vp[3][8];
#pragma unroll
  for (int j = 0; j < 8; ++j) {
    float v = W[c * 16384 + (dg * 16 + o * 8 + j) * 16 + n];
    split3(v, vp[0][j], vp[1][j], vp[2][j]);
  }
#pragma unroll
  for (int pp = 0; pp < 3; ++pp) {
    size_t base = ((((size_t)dg * 8 + c) * 3 + pp) * 16 + n) * 16 + o * 8;
    *(bf16x8*)(wfrag + base) = *(bf16x8*)vp[pp];
  }
}

// ---------------- K3: projection GEMM (frag-major B, fused row-sums) --------
// Grid (64 rowgroups, 8 ks) x 256 = 512 blocks. Block: 128 rows x 128 cols x
// K=128 d (8 d-groups of 16). Wave = 32 rows (2 M-tiles). x loaded direct,
// split3 in-register. B loads: one dense 1KB region per inst (frag-major),
// shared across block's waves via L1. Row sums for mu fall out for free.
__global__ __launch_bounds__(256) void k_proj(const float* __restrict__ x,
                                              const unsigned short* __restrict__ wfrag,
                                              float* __restrict__ part,
                                              float* __restrict__ psum) {
  const int t = threadIdx.x;
  const int lane = t & 63, w = t >> 6;
  const int r0 = blockIdx.x * 128;
  const int ks = blockIdx.y;
  const int q = lane >> 4, n16 = lane & 15, oct = q & 1;
  const bool qlt2 = (q < 2);
  const int p1 = qlt2 ? 0 : 1, p2 = qlt2 ? 1 : 0, p3 = qlt2 ? 2 : 0;

  f32x4 acc[2][8];
#pragma unroll
  for (int mt = 0; mt < 2; ++mt)
#pragma unroll
    for (int h = 0; h < 8; ++h) acc[mt][h] = (f32x4){0.f, 0.f, 0.f, 0.f};
  float ps[2] = {0.f, 0.f};

  for (int dg = 0; dg < 8; ++dg) {
    const int dq = ks * 128 + dg * 16 + oct * 8;
    bf16x8 a1[2], a3[2];
#pragma unroll
    for (int mt = 0; mt < 2; ++mt) {
      const int row = r0 + w * 32 + mt * 16 + n16;
      float4 xa = *(const float4*)(x + (size_t)row * 1024 + dq);
      float4 xb = *(const float4*)(x + (size_t)row * 1024 + dq + 4);
      float xf[8] = {xa.x, xa.y, xa.z, xa.w, xb.x, xb.y, xb.z, xb.w};
      ps[mt] += ((xf[0] + xf[1]) + (xf[2] + xf[3])) +
                ((xf[4] + xf[5]) + (xf[6] + xf[7]));
      __attribute__((aligned(16))) unsigned short s1[8], s3[8];
#pragma unroll
      for (int j = 0; j < 8; ++j) {
        unsigned short hh, mm, ll;
        split3(xf[j], hh, mm, ll);
        s1[j] = qlt2 ? hh : mm;
        s3[j] = qlt2 ? hh : ll;
      }
      a1[mt] = *(bf16x8*)s1;
      a3[mt] = *(bf16x8*)s3;
    }
#pragma unroll
    for (int hh = 0; hh < 8; ++hh) {
      // R10 FIX: global d-group (ks*8+dg), not local dg.
      size_t b0 = (((size_t)((ks * 8 + dg) * 8 + hh) * 3) * 16 + n16) * 16 + oct * 8;
      bf16x8 b1 = *(const bf16x8*)(wfrag + b0 + p1 * 256);
      bf16x8 b2 = *(const bf16x8*)(wfrag + b0 + p2 * 256);
      bf16x8 b3 = *(const bf16x8*)(wfrag + b0 + p3 * 256);
#pragma unroll
      for (int mt = 0; mt < 2; ++mt) {
        acc[mt][hh] = __builtin_amdgcn_mfma_f32_16x16x32_bf16(a1[mt], b1, acc[mt][hh], 0, 0, 0);
        acc[mt][hh] = __builtin_amdgcn_mfma_f32_16x16x32_bf16(a1[mt], b2, acc[mt][hh], 0, 0, 0);
        acc[mt][hh] = __builtin_amdgcn_mfma_f32_16x16x32_bf16(a3[mt], b3, acc[mt][hh], 0, 0, 0);
      }
    }
  }

  float* po = part + ((size_t)ks * 8192 + r0 + w * 32) * 128;
#pragma unroll
  for (int mt = 0; mt < 2; ++mt)
#pragma unroll
    for (int hh = 0; hh < 8; ++hh)
#pragma unroll
      for (int r = 0; r < 4; ++r)
        po[(size_t)(mt * 16 + q * 4 + r) * 128 + hh * 16 + n16] = acc[mt][hh][r];

  // row-sum partials: q0 holds oct0 of each d-group, q1 oct1 (q2/q3 dup).
  float pr0 = ps[0] + __shfl_xor(ps[0], 16);
  float pr1 = ps[1] + __shfl_xor(ps[1], 16);
  if (lane < 16) {
    psum[(size_t)ks * 8192 + r0 + w * 32 + n16] = pr0;
    psum[(size_t)ks * 8192 + r0 + w * 32 + 16 + n16] = pr1;
  }
}

// ---------------- K3b: combine 8 K-slices - mu*colsum, emit bf16 splits -----
__global__ __launch_bounds__(256) void k_combine(const float* __restrict__ part,
                                                 const float* __restrict__ psum,
                                                 const float* __restrict__ csum,
                                                 unsigned short* __restrict__ ph,
                                                 unsigned short* __restrict__ pm,
                                                 unsigned short* __restrict__ pl) {
  int idx = blockIdx.x * 256 + threadIdx.x;   // f4 index, 262144 total
  int row = idx >> 5, c4 = (idx & 31) * 4;
  float4 a = {0.f, 0.f, 0.f, 0.f};
  float msum = 0.f;
#pragma unroll
  for (int s = 0; s < 8; ++s) {
    float4 p = *(const float4*)(part + ((size_t)s * 8192 + row) * 128 + c4);
    a.x += p.x; a.y += p.y; a.z += p.z; a.w += p.w;
    msum += psum[(size_t)s * 8192 + row];
  }
  float m = msum * (1.0f / 1024.0f);
  float4 cs = *(const float4*)(csum + c4);
  float o[4] = {a.x - m * cs.x, a.y - m * cs.y, a.z - m * cs.z, a.w - m * cs.w};
  __attribute__((aligned(8))) unsigned short vh[4], vm[4], vl[4];
#pragma unroll
  for (int k = 0; k < 4; ++k) split3(o[k], vh[k], vm[k], vl[k]);
  int head = c4 >> 4, e0 = c4 & 15;
  size_t base = ((size_t)head * 8192 + row) * 16 + e0;
  *(short4*)(ph + base) = *(short4*)vh;
  *(short4*)(pm + base) = *(short4*)vm;
  *(short4*)(pl + base) = *(short4*)vl;
}

// ---------------- K4: MFMA argmax partials (frag-major codebook) ------------
// Grid (16 rowgroups, 8 heads, 4 code-quarters) x 256 = 512 blocks. Wave =
// 128 rows (8 row-tiles, A-frags in regs, reused over 32 code-tiles -> B
// reuse x8). B loads: dense 1KB regions from cfrag (L2-hot, 1.5MB). Per-lane
// codes ascend -> strict '>' = first max; cross-lane shfl_xor(w16)
// lexicographic; quarters merged in k_amred.
__global__ __launch_bounds__(256) void k_argmax(
    const unsigned short* __restrict__ ph, const unsigned short* __restrict__ pm,
    const unsigned short* __restrict__ pl, const unsigned short* __restrict__ cfrag,
    float* __restrict__ amv, int* __restrict__ ami) {
  const int t = threadIdx.x;
  const int lane = t & 63, w = t >> 6;
  const int h = blockIdx.y;
  const int z = blockIdx.z;
  const int r0 = blockIdx.x * 512 + w * 128;
  const int q = lane >> 4, n16 = lane & 15;
  const int ehalf = (q & 1) * 8;
  const bool qlt2 = (q < 2);
  const int p1 = qlt2 ? 0 : 1, p2 = qlt2 ? 1 : 0, p3 = qlt2 ? 2 : 0;

  const unsigned short* pa1 = qlt2 ? ph : pm;   // A1 = [h|m]
  const unsigned short* pa3 = qlt2 ? ph : pl;   // A3 = [h|l]
  bf16x8 a1[8], a3[8];
#pragma unroll
  for (int rt = 0; rt < 8; ++rt) {
    size_t off = ((size_t)h * 8192 + r0 + rt * 16 + n16) * 16 + ehalf;
    a1[rt] = *(const bf16x8*)(pa1 + off);
    a3[rt] = *(const bf16x8*)(pa3 + off);
  }

  float best[8][4];
  int   bidx[8][4];
#pragma unroll
  for (int rt = 0; rt < 8; ++rt)
#pragma unroll
    for (int r = 0; r < 4; ++r) { best[rt][r] = -3.402823466e38f; bidx[rt][r] = 0; }

  for (int tile = 0; tile < 32; ++tile) {
    size_t b0 = ((((size_t)h * 128 + z * 32 + tile) * 3) * 16 + n16) * 16 + ehalf;
    bf16x8 b1 = *(const bf16x8*)(cfrag + b0 + p1 * 256);
    bf16x8 b2 = *(const bf16x8*)(cfrag + b0 + p2 * 256);
    bf16x8 b3 = *(const bf16x8*)(cfrag + b0 + p3 * 256);
    const int code = z * 512 + tile * 16 + n16;
#pragma unroll
    for (int rt = 0; rt < 8; ++rt) {
      f32x4 acc = {0.f, 0.f, 0.f, 0.f};
      acc = __builtin_amdgcn_mfma_f32_16x16x32_bf16(a1[rt], b1, acc, 0, 0, 0);
      acc = __builtin_amdgcn_mfma_f32_16x16x32_bf16(a1[rt], b2, acc, 0, 0, 0);
      acc = __builtin_amdgcn_mfma_f32_16x16x32_bf16(a3[rt], b3, acc, 0, 0, 0);
#pragma unroll
      for (int r = 0; r < 4; ++r)
        if (acc[r] > best[rt][r]) { best[rt][r] = acc[r]; bidx[rt][r] = code; }
    }
  }

#pragma unroll
  for (int off = 8; off >= 1; off >>= 1) {
#pragma unroll
    for (int rt = 0; rt < 8; ++rt)
#pragma unroll
      for (int r = 0; r < 4; ++r) {
        float ov = __shfl_xor(best[rt][r], off, 16);
        int   oi = __shfl_xor(bidx[rt][r], off, 16);
        if (ov > best[rt][r] || (ov == best[rt][r] && oi < bidx[rt][r])) {
          best[rt][r] = ov; bidx[rt][r] = oi;
        }
      }
  }
  if (n16 == 0) {
#pragma unroll
    for (int rt = 0; rt < 8; ++rt)
#pragma unroll
      for (int r = 0; r < 4; ++r) {
        int row = r0 + rt * 16 + q * 4 + r;
        size_t o = (size_t)z * 65536 + (size_t)row * 8 + h;
        amv[o] = best[rt][r]; ami[o] = bidx[rt][r];
      }
  }
}

// ---------------- K5: merge the four code-quarters --------------------------
__global__ __launch_bounds__(256) void k_amred(const float* __restrict__ amv,
                                               const int* __restrict__ ami,
                                               int* __restrict__ out) {
  int i = blockIdx.x * 256 + threadIdx.x;   // 65536
  float bv = amv[i]; int bi = ami[i];
#pragma unroll
  for (int z = 1; z < 4; ++z) {
    float v = amv[(size_t)z * 65536 + i];
    if (v > bv) { bv = v; bi = ami[(size_t)z * 65536 + i]; }
  }
  out[i] = bi;
}

extern "C" void kernel_launch(void* const* d_in, const int* in_sizes, int n_in,
                              void* d_out, int out_size, void* d_ws, size_t ws_size,
                              hipStream_t stream) {
  (void)in_sizes; (void)n_in; (void)out_size; (void)ws_size;
  const float* x  = (const float*)d_in[0];   // [4,2048,1024]
  const float* rp = (const float*)d_in[1];   // [8,1024,16]
  const float* cb = (const float*)d_in[2];   // [8,2048,16]
  int* out = (int*)d_out;                    // [8192,8] int32

  float* ws = (float*)d_ws;
  float*          csum  = ws;                              // 128
  float*          psum  = ws + 128;                        // 65536
  float*          part  = ws + 65664;                      // 8388608
  float*          amv   = ws + 8454272;                    // 262144
  int*            ami   = (int*)(ws + 8716416);            // 262144
  unsigned short* wfrag = (unsigned short*)(ws + 8978560); // 393216 sh
  unsigned short* cfrag = (unsigned short*)(ws + 9175168); // 786432 sh
  unsigned short* ph    = (unsigned short*)(ws + 9568384); // 1048576 sh each
  unsigned short* pm    = (unsigned short*)(ws + 10092672);
  unsigned short* pl    = (unsigned short*)(ws + 10616960); // end ~44.6 MB

  hipLaunchKernelGGL(k_cbnorm,  dim3(64),        dim3(256), 0, stream, cb, cfrag);
  hipLaunchKernelGGL(k_colsum,  dim3(8),         dim3(256), 0, stream, rp, csum);
  hipLaunchKernelGGL(k_wsplit,  dim3(64),        dim3(256), 0, stream, rp, wfrag);
  hipLaunchKernelGGL(k_proj,    dim3(64, 8),     dim3(256), 0, stream, x, wfrag, part, psum);
  hipLaunchKernelGGL(k_combine, dim3(1024),      dim3(256), 0, stream, part, psum, csum, ph, pm, pl);
  hipLaunchKernelGGL(k_argmax,  dim3(16, 8, 4),  dim3(256), 0, stream, ph, pm, pl, cfrag, amv, ami);
  hipLaunchKernelGGL(k_amred,   dim3(256),       dim3(256), 0, stream, amv, ami, out);
}

// Round 11
// 161.119 us; speedup vs baseline: 1.3922x; 1.0092x over previous
//
#include <hip/hip_runtime.h>
#include <math.h>

// b=4,n=2048 -> 8192 rows; d=1024; h=8; e=16; cs=2048. Output int32 [8192,8].
// argmax_c q.cbn_c == argmax_c ((x.W - mu*colsum(W)) . cbn_c): LN 1/sigma and
// q-norm are positive per-(row,head) scalars -> cancel. Codebook normalized fp64.
//
// MFMA path (verified R7/R10): fp32 operands split into 3 bf16 parts h,m,l
// (8+8+8 >= 24 mantissa bits; bf16 exp = fp32 -> no subnormal flush).
// v_p*v_c ~= hh + hm+mh + hl+mm+lh via 3 K=32 bf16 MFMAs, quad-packed:
// quads 0,1 carry part-A of the pair, quads 2,3 part-B. Dropped ml/lm/ll
// ~2^-25 rel. Frag-major B layouts (R9/R10).
//
// R11: (a) proj does full K=1024 per block with cross-wave LDS reduction and
// emits ph/pm/pl directly (part/psum/combine/mu all eliminated);
// (b) argmax stages the per-(h,z) 24KB codebook chunk into LDS once.

typedef short bf16x8 __attribute__((ext_vector_type(8)));
typedef float f32x4 __attribute__((ext_vector_type(4)));

__device__ __forceinline__ void stage16(const float* g, float* lds_base) {
  __builtin_amdgcn_global_load_lds(
      (const __attribute__((address_space(1))) void*)g,
      (__attribute__((address_space(3))) void*)lds_base, 16, 0, 0);
}

__device__ __forceinline__ unsigned short f2bf(float f) {
  unsigned u = __builtin_bit_cast(unsigned, f);
  unsigned r = (u + 0x7FFFu + ((u >> 16) & 1u)) >> 16;   // RNE
  return (unsigned short)r;
}
__device__ __forceinline__ float bf2f(unsigned short b) {
  return __builtin_bit_cast(float, (unsigned)b << 16);
}
__device__ __forceinline__ void split3(float v, unsigned short& h,
                                       unsigned short& m, unsigned short& l) {
  h = f2bf(v);
  float r = v - bf2f(h);
  m = f2bf(r);
  float r2 = r - bf2f(m);
  l = f2bf(r2);
}

// ---------------- K1: normalize codebook (fp64) -> frag-major cfrag ---------
// cfrag layout: [h(8)][tile(128)][p(3)][n(16)][oct(2)][j(8)] shorts (1.5 MB).
__global__ __launch_bounds__(256) void k_cbnorm(const float* __restrict__ cb,
                                                unsigned short* __restrict__ cfrag) {
  int v = blockIdx.x * 256 + threadIdx.x;      // 0..16383 code vectors
  int h = v >> 11, c = v & 2047, tl = c >> 4, n = c & 15;
  const float4* p = (const float4*)(cb + (size_t)v * 16);
  float4 q0 = p[0], q1 = p[1], q2 = p[2], q3 = p[3];
  float f[16] = {q0.x,q0.y,q0.z,q0.w, q1.x,q1.y,q1.z,q1.w,
                 q2.x,q2.y,q2.z,q2.w, q3.x,q3.y,q3.z,q3.w};
  double s = 0.0;
#pragma unroll
  for (int i = 0; i < 16; ++i) s += (double)f[i] * (double)f[i];
  double inv = 1.0 / sqrt(s + 1e-12);
  __attribute__((aligned(16))) unsigned short vp[3][16];
#pragma unroll
  for (int i = 0; i < 16; ++i)
    split3((float)((double)f[i] * inv), vp[0][i], vp[1][i], vp[2][i]);
#pragma unroll
  for (int pp = 0; pp < 3; ++pp) {
    size_t base = ((((size_t)h * 128 + tl) * 3 + pp) * 16 + n) * 16;
    ((bf16x8*)(cfrag + base))[0] = ((bf16x8*)vp[pp])[0];
    ((bf16x8*)(cfrag + base))[1] = ((bf16x8*)vp[pp])[1];
  }
}

// ---------------- K2: column sums of W --------------------------------------
__global__ __launch_bounds__(256) void k_colsum(const float* __restrict__ W,
                                                float* __restrict__ cs) {
  __shared__ float red[16][17];
  int h = blockIdx.x;
  int e = threadIdx.x & 15, part = threadIdx.x >> 4;
  const float* base = W + h * 16384 + e;
  float s = 0.f;
  int d0 = part * 64;
  for (int i = 0; i < 64; ++i) s += base[(d0 + i) * 16];
  red[e][part] = s;
  __syncthreads();
  if (threadIdx.x < 16) {
    float t = 0.f;
#pragma unroll
    for (int p = 0; p < 16; ++p) t += red[threadIdx.x][p];
    cs[h * 16 + threadIdx.x] = t;
  }
}

// ---------------- K2b: W -> frag-major bf16-split wfrag ---------------------
// wfrag layout: [dg(64)][c=head(8)][p(3)][n=e(16)][oct(2)][j(8)] (768 KB).
__global__ __launch_bounds__(256) void k_wsplit(const float* __restrict__ W,
                                                unsigned short* __restrict__ wfrag) {
  int id = blockIdx.x * 256 + threadIdx.x;     // 0..16383
  int o = id & 1, n = (id >> 1) & 15, c = (id >> 5) & 7, dg = id >> 8;
  __attribute__((aligned(16))) unsigned short vp[3][8];
#pragma unroll
  for (int j = 0; j < 8; ++j) {
    float v = W[c * 16384 + (dg * 16 + o * 8 + j) * 16 + n];
    split3(v, vp[0][j], vp[1][j], vp[2][j]);
  }
#pragma unroll
  for (int pp = 0; pp < 3; ++pp) {
    size_t base = ((((size_t)dg * 8 + c) * 3 + pp) * 16 + n) * 16 + o * 8;
    *(bf16x8*)(wfrag + base) = *(bf16x8*)vp[pp];
  }
}

// ---------------- K3: fused projection (full K, in-block reduce) ------------
// Grid 512 x 256. Block = 16 rows x 128 cols x K=1024; wave w covers
// d-groups [w*16, w*16+16), acc in regs. Cross-wave reduce via LDS
// (pitch-33 -> conflict-free), then mu (fused row-sums) + csum correction,
// split3, and direct ph/pm/pl emission. part/psum/combine/mu eliminated.
__global__ __launch_bounds__(256) void k_proj(const float* __restrict__ x,
                                              const unsigned short* __restrict__ wfrag,
                                              const float* __restrict__ csum,
                                              unsigned short* __restrict__ ph,
                                              unsigned short* __restrict__ pm,
                                              unsigned short* __restrict__ pl) {
  __shared__ float sAcc[4][64][33];   // 33.8 KB
  __shared__ float sPs[4][2][16];
  __shared__ float sMu[16];
  const int t = threadIdx.x;
  const int lane = t & 63, w = t >> 6;
  const int r0 = blockIdx.x * 16;
  const int q = lane >> 4, n16 = lane & 15, oct = q & 1;
  const bool qlt2 = (q < 2);
  const int p1 = qlt2 ? 0 : 1, p2 = qlt2 ? 1 : 0, p3 = qlt2 ? 2 : 0;
  const int row = r0 + n16;

  f32x4 acc[8];
#pragma unroll
  for (int h = 0; h < 8; ++h) acc[h] = (f32x4){0.f, 0.f, 0.f, 0.f};
  float ps = 0.f;

  for (int dg2 = 0; dg2 < 16; ++dg2) {
    const int dg = w * 16 + dg2;
    const int dq = dg * 16 + oct * 8;
    float4 xa = *(const float4*)(x + (size_t)row * 1024 + dq);
    float4 xb = *(const float4*)(x + (size_t)row * 1024 + dq + 4);
    float xf[8] = {xa.x, xa.y, xa.z, xa.w, xb.x, xb.y, xb.z, xb.w};
    ps += ((xf[0] + xf[1]) + (xf[2] + xf[3])) +
          ((xf[4] + xf[5]) + (xf[6] + xf[7]));
    __attribute__((aligned(16))) unsigned short s1[8], s3[8];
#pragma unroll
    for (int j = 0; j < 8; ++j) {
      unsigned short hh, mm, ll;
      split3(xf[j], hh, mm, ll);
      s1[j] = qlt2 ? hh : mm;
      s3[j] = qlt2 ? hh : ll;
    }
    bf16x8 a1 = *(bf16x8*)s1;
    bf16x8 a3 = *(bf16x8*)s3;
#pragma unroll
    for (int hh = 0; hh < 8; ++hh) {
      size_t b0 = (((size_t)(dg * 8 + hh) * 3) * 16 + n16) * 16 + oct * 8;
      bf16x8 b1 = *(const bf16x8*)(wfrag + b0 + p1 * 256);
      bf16x8 b2 = *(const bf16x8*)(wfrag + b0 + p2 * 256);
      bf16x8 b3 = *(const bf16x8*)(wfrag + b0 + p3 * 256);
      acc[hh] = __builtin_amdgcn_mfma_f32_16x16x32_bf16(a1, b1, acc[hh], 0, 0, 0);
      acc[hh] = __builtin_amdgcn_mfma_f32_16x16x32_bf16(a1, b2, acc[hh], 0, 0, 0);
      acc[hh] = __builtin_amdgcn_mfma_f32_16x16x32_bf16(a3, b3, acc[hh], 0, 0, 0);
    }
  }

#pragma unroll
  for (int hh = 0; hh < 8; ++hh)
#pragma unroll
    for (int r = 0; r < 4; ++r) sAcc[w][lane][hh * 4 + r] = acc[hh][r];
  if (q < 2) sPs[w][q][n16] = ps;
  __syncthreads();
  if (t < 16) {
    float s = 0.f;
#pragma unroll
    for (int w2 = 0; w2 < 4; ++w2) s += sPs[w2][0][t] + sPs[w2][1][t];
    sMu[t] = s * (1.0f / 1024.0f);
  }
  __syncthreads();

  // epilogue: thread (g = t>>6, l = t&63) handles heads {2g, 2g+1}
  const int l = t & 63, g = t >> 6;
  const int lq = l >> 4, ln = l & 15;
#pragma unroll
  for (int hh2 = 0; hh2 < 2; ++hh2) {
    const int head = g * 2 + hh2;
    const float cs = csum[head * 16 + ln];
#pragma unroll
    for (int r = 0; r < 4; ++r) {
      const int f = head * 4 + r;
      float v = ((sAcc[0][l][f] + sAcc[1][l][f]) +
                 (sAcc[2][l][f] + sAcc[3][l][f]));
      const int row16 = lq * 4 + r;
      float tv = v - sMu[row16] * cs;
      unsigned short vh, vm, vl;
      split3(tv, vh, vm, vl);
      size_t base = ((size_t)head * 8192 + r0 + row16) * 16 + ln;
      ph[base] = vh; pm[base] = vm; pl[base] = vl;
    }
  }
}

// ---------------- K4: MFMA argmax partials (LDS-staged codebook) ------------
// Grid (32 rowgroups, 8 heads, 8 code-eighths) x 256 = 2048 blocks (8/CU).
// Per block: the (h,z) cfrag chunk (16 tiles x 3 parts x 512B = 24KB,
// contiguous) staged once into LDS via global_load_lds; one barrier. Wave =
// 64 rows (4 row-tiles, A-frags in regs). Per tile: 3 LDS b128 reads + 12
// MFMAs + compares. Per-lane codes ascend -> strict '>' = first max;
// cross-lane shfl_xor(w16) lexicographic; eighths merged in k_amred.
__global__ __launch_bounds__(256) void k_argmax(
    const unsigned short* __restrict__ ph, const unsigned short* __restrict__ pm,
    const unsigned short* __restrict__ pl, const unsigned short* __restrict__ cfrag,
    float* __restrict__ amv, int* __restrict__ ami) {
  __shared__ __align__(16) unsigned short sB[12288];   // 24 KB
  const int t = threadIdx.x;
  const int lane = t & 63, w = t >> 6;
  const int h = blockIdx.y;
  const int z = blockIdx.z;
  const int r0 = blockIdx.x * 256 + w * 64;
  const int q = lane >> 4, n16 = lane & 15;
  const int ehalf = (q & 1) * 8;
  const bool qlt2 = (q < 2);
  const int p1 = qlt2 ? 0 : 1, p2 = qlt2 ? 1 : 0, p3 = qlt2 ? 2 : 0;

  // stage the (h,z) codebook chunk: 1536 x 16B, 6 per lane
  const float* src = (const float*)(cfrag + ((size_t)(h * 128 + z * 16) * 3) * 256);
#pragma unroll
  for (int i = 0; i < 6; ++i)
    stage16(src + ((size_t)((i * 4 + w) * 64) + lane) * 4,
            (float*)sB + (i * 4 + w) * 256);

  const unsigned short* pa1 = qlt2 ? ph : pm;   // A1 = [h|m]
  const unsigned short* pa3 = qlt2 ? ph : pl;   // A3 = [h|l]
  bf16x8 a1[4], a3[4];
#pragma unroll
  for (int rt = 0; rt < 4; ++rt) {
    size_t off = ((size_t)h * 8192 + r0 + rt * 16 + n16) * 16 + ehalf;
    a1[rt] = *(const bf16x8*)(pa1 + off);
    a3[rt] = *(const bf16x8*)(pa3 + off);
  }

  float best[4][4];
  int   bidx[4][4];
#pragma unroll
  for (int rt = 0; rt < 4; ++rt)
#pragma unroll
    for (int r = 0; r < 4; ++r) { best[rt][r] = -3.402823466e38f; bidx[rt][r] = 0; }

  __syncthreads();

  for (int tile = 0; tile < 16; ++tile) {
    const int b0 = tile * 768 + n16 * 16 + ehalf;
    bf16x8 b1 = *(const bf16x8*)(sB + b0 + p1 * 256);
    bf16x8 b2 = *(const bf16x8*)(sB + b0 + p2 * 256);
    bf16x8 b3 = *(const bf16x8*)(sB + b0 + p3 * 256);
    const int code = z * 256 + tile * 16 + n16;
#pragma unroll
    for (int rt = 0; rt < 4; ++rt) {
      f32x4 acc = {0.f, 0.f, 0.f, 0.f};
      acc = __builtin_amdgcn_mfma_f32_16x16x32_bf16(a1[rt], b1, acc, 0, 0, 0);
      acc = __builtin_amdgcn_mfma_f32_16x16x32_bf16(a1[rt], b2, acc, 0, 0, 0);
      acc = __builtin_amdgcn_mfma_f32_16x16x32_bf16(a3[rt], b3, acc, 0, 0, 0);
#pragma unroll
      for (int r = 0; r < 4; ++r)
        if (acc[r] > best[rt][r]) { best[rt][r] = acc[r]; bidx[rt][r] = code; }
    }
  }

#pragma unroll
  for (int off = 8; off >= 1; off >>= 1) {
#pragma unroll
    for (int rt = 0; rt < 4; ++rt)
#pragma unroll
      for (int r = 0; r < 4; ++r) {
        float ov = __shfl_xor(best[rt][r], off, 16);
        int   oi = __shfl_xor(bidx[rt][r], off, 16);
        if (ov > best[rt][r] || (ov == best[rt][r] && oi < bidx[rt][r])) {
          best[rt][r] = ov; bidx[rt][r] = oi;
        }
      }
  }
  if (n16 == 0) {
#pragma unroll
    for (int rt = 0; rt < 4; ++rt)
#pragma unroll
      for (int r = 0; r < 4; ++r) {
        int row = r0 + rt * 16 + q * 4 + r;
        size_t o = (size_t)z * 65536 + (size_t)row * 8 + h;
        amv[o] = best[rt][r]; ami[o] = bidx[rt][r];
      }
  }
}

// ---------------- K5: merge the eight code-eighths --------------------------
__global__ __launch_bounds__(256) void k_amred(const float* __restrict__ amv,
                                               const int* __restrict__ ami,
                                               int* __restrict__ out) {
  int i = blockIdx.x * 256 + threadIdx.x;   // 65536
  float bv = amv[i]; int bi = ami[i];
#pragma unroll
  for (int z = 1; z < 8; ++z) {
    float v = amv[(size_t)z * 65536 + i];
    if (v > bv) { bv = v; bi = ami[(size_t)z * 65536 + i]; }
  }
  out[i] = bi;
}

extern "C" void kernel_launch(void* const* d_in, const int* in_sizes, int n_in,
                              void* d_out, int out_size, void* d_ws, size_t ws_size,
                              hipStream_t stream) {
  (void)in_sizes; (void)n_in; (void)out_size; (void)ws_size;
  const float* x  = (const float*)d_in[0];   // [4,2048,1024]
  const float* rp = (const float*)d_in[1];   // [8,1024,16]
  const float* cb = (const float*)d_in[2];   // [8,2048,16]
  int* out = (int*)d_out;                    // [8192,8] int32

  float* ws = (float*)d_ws;
  float*          csum  = ws;                              // 128
  float*          amv   = ws + 128;                        // 524288
  int*            ami   = (int*)(ws + 524416);             // 524288
  unsigned short* wfrag = (unsigned short*)(ws + 1048704); // 393216 sh
  unsigned short* cfrag = (unsigned short*)(ws + 1245312); // 786432 sh
  unsigned short* ph    = (unsigned short*)(ws + 1638528); // 1048576 sh each
  unsigned short* pm    = (unsigned short*)(ws + 2162816);
  unsigned short* pl    = (unsigned short*)(ws + 2687104); // end ~12.8 MB

  hipLaunchKernelGGL(k_cbnorm,  dim3(64),        dim3(256), 0, stream, cb, cfrag);
  hipLaunchKernelGGL(k_colsum,  dim3(8),         dim3(256), 0, stream, rp, csum);
  hipLaunchKernelGGL(k_wsplit,  dim3(64),        dim3(256), 0, stream, rp, wfrag);
  hipLaunchKernelGGL(k_proj,    dim3(512),       dim3(256), 0, stream, x, wfrag, csum, ph, pm, pl);
  hipLaunchKernelGGL(k_argmax,  dim3(32, 8, 8),  dim3(256), 0, stream, ph, pm, pl, cfrag, amv, ami);
  hipLaunchKernelGGL(k_amred,   dim3(256),       dim3(256), 0, stream, amv, ami, out);
}

// Round 12
// 147.434 us; speedup vs baseline: 1.5214x; 1.0928x over previous
//
#include <hip/hip_runtime.h>
#include <math.h>

// b=4,n=2048 -> 8192 rows; d=1024; h=8; e=16; cs=2048. Output int32 [8192,8].
// argmax_c q.cbn_c == argmax_c ((x.W - mu*colsum(W)) . cbn_c): LN 1/sigma and
// q-norm are positive per-(row,head) scalars -> cancel. Codebook normalized fp64.
//
// MFMA path (verified R7/R10): fp32 operands split into 3 bf16 parts h,m,l
// (8+8+8 >= 24 mantissa bits; bf16 exp = fp32 -> no subnormal flush).
// v_p*v_c ~= hh + hm+mh + hl+mm+lh via 3 K=32 bf16 MFMAs, quad-packed:
// quads 0,1 carry part-A of the pair, quads 2,3 part-B. Dropped ml/lm/ll
// ~2^-25 rel. Frag-major B layouts (R9/R10).
//
// R12: (a) proj 512-thread blocks, 8-wave K-split + wave-pair LDS reduce
// (16 waves/CU; was 8) + unroll-4 load hoisting; (b) cbnorm/colsum/wsplit
// fused into one k_prep launch (kills 2 launch gaps).

typedef short bf16x8 __attribute__((ext_vector_type(8)));
typedef float f32x4 __attribute__((ext_vector_type(4)));

__device__ __forceinline__ void stage16(const float* g, float* lds_base) {
  __builtin_amdgcn_global_load_lds(
      (const __attribute__((address_space(1))) void*)g,
      (__attribute__((address_space(3))) void*)lds_base, 16, 0, 0);
}

__device__ __forceinline__ unsigned short f2bf(float f) {
  unsigned u = __builtin_bit_cast(unsigned, f);
  unsigned r = (u + 0x7FFFu + ((u >> 16) & 1u)) >> 16;   // RNE
  return (unsigned short)r;
}
__device__ __forceinline__ float bf2f(unsigned short b) {
  return __builtin_bit_cast(float, (unsigned)b << 16);
}
__device__ __forceinline__ void split3(float v, unsigned short& h,
                                       unsigned short& m, unsigned short& l) {
  h = f2bf(v);
  float r = v - bf2f(h);
  m = f2bf(r);
  float r2 = r - bf2f(m);
  l = f2bf(r2);
}

// ---------------- K1: fused prep: cbnorm | colsum | wsplit ------------------
// grid 136: [0,64) cbnorm -> cfrag [h][tile][p][n][oct][j] (1.5MB);
// [64,72) colsum -> csum[128]; [72,136) wsplit -> wfrag [dg][c][p][n][oct][j].
__global__ __launch_bounds__(256) void k_prep(const float* __restrict__ cb,
                                              const float* __restrict__ W,
                                              unsigned short* __restrict__ cfrag,
                                              float* __restrict__ csum,
                                              unsigned short* __restrict__ wfrag) {
  __shared__ float red[16][17];
  const int bid = blockIdx.x;
  const int t = threadIdx.x;
  if (bid < 64) {            // ---- cbnorm (fp64 normalize + bf16 3-split)
    int v = bid * 256 + t;
    int h = v >> 11, c = v & 2047, tl = c >> 4, n = c & 15;
    const float4* p = (const float4*)(cb + (size_t)v * 16);
    float4 q0 = p[0], q1 = p[1], q2 = p[2], q3 = p[3];
    float f[16] = {q0.x,q0.y,q0.z,q0.w, q1.x,q1.y,q1.z,q1.w,
                   q2.x,q2.y,q2.z,q2.w, q3.x,q3.y,q3.z,q3.w};
    double s = 0.0;
#pragma unroll
    for (int i = 0; i < 16; ++i) s += (double)f[i] * (double)f[i];
    double inv = 1.0 / sqrt(s + 1e-12);
    __attribute__((aligned(16))) unsigned short vp[3][16];
#pragma unroll
    for (int i = 0; i < 16; ++i)
      split3((float)((double)f[i] * inv), vp[0][i], vp[1][i], vp[2][i]);
#pragma unroll
    for (int pp = 0; pp < 3; ++pp) {
      size_t base = ((((size_t)h * 128 + tl) * 3 + pp) * 16 + n) * 16;
      ((bf16x8*)(cfrag + base))[0] = ((bf16x8*)vp[pp])[0];
      ((bf16x8*)(cfrag + base))[1] = ((bf16x8*)vp[pp])[1];
    }
  } else if (bid < 72) {     // ---- colsum
    int h = bid - 64;
    int e = t & 15, part = t >> 4;
    const float* base = W + h * 16384 + e;
    float s = 0.f;
    int d0 = part * 64;
    for (int i = 0; i < 64; ++i) s += base[(d0 + i) * 16];
    red[e][part] = s;
    __syncthreads();
    if (t < 16) {
      float tt = 0.f;
#pragma unroll
      for (int p = 0; p < 16; ++p) tt += red[t][p];
      csum[h * 16 + t] = tt;
    }
  } else {                   // ---- wsplit
    int id = (bid - 72) * 256 + t;
    int o = id & 1, n = (id >> 1) & 15, c = (id >> 5) & 7, dg = id >> 8;
    __attribute__((aligned(16))) unsigned short vp[3][8];
#pragma unroll
    for (int j = 0; j < 8; ++j) {
      float v = W[c * 16384 + (dg * 16 + o * 8 + j) * 16 + n];
      split3(v, vp[0][j], vp[1][j], vp[2][j]);
    }
#pragma unroll
    for (int pp = 0; pp < 3; ++pp) {
      size_t base = ((((size_t)dg * 8 + c) * 3 + pp) * 16 + n) * 16 + o * 8;
      *(bf16x8*)(wfrag + base) = *(bf16x8*)vp[pp];
    }
  }
}

// ---------------- K3: fused projection (full K, 8-wave split) ---------------
// Grid 512 x 512 threads. Block = 16 rows x 128 cols x K=1024; wave w covers
// d-groups [w*8, w*8+8). Wave-pair reduce (4-7 dump, 0-3 add: LDS stays
// <64KB), then mu (fused row-sums) + csum, split3, direct ph/pm/pl emission.
__global__ __launch_bounds__(512) void k_proj(const float* __restrict__ x,
                                              const unsigned short* __restrict__ wfrag,
                                              const float* __restrict__ csum,
                                              unsigned short* __restrict__ ph,
                                              unsigned short* __restrict__ pm,
                                              unsigned short* __restrict__ pl) {
  __shared__ float sAcc[4][64][33];   // 33.8 KB
  __shared__ float sPs[8][2][16];
  __shared__ float sMu[16];
  const int t = threadIdx.x;
  const int lane = t & 63, w = t >> 6;        // w 0..7
  const int r0 = blockIdx.x * 16;
  const int q = lane >> 4, n16 = lane & 15, oct = q & 1;
  const bool qlt2 = (q < 2);
  const int p1 = qlt2 ? 0 : 1, p2 = qlt2 ? 1 : 0, p3 = qlt2 ? 2 : 0;
  const int row = r0 + n16;

  f32x4 acc[8];
#pragma unroll
  for (int h = 0; h < 8; ++h) acc[h] = (f32x4){0.f, 0.f, 0.f, 0.f};
  float ps = 0.f;

#pragma unroll 4
  for (int dg2 = 0; dg2 < 8; ++dg2) {
    const int dg = w * 8 + dg2;
    const int dq = dg * 16 + oct * 8;
    float4 xa = *(const float4*)(x + (size_t)row * 1024 + dq);
    float4 xb = *(const float4*)(x + (size_t)row * 1024 + dq + 4);
    float xf[8] = {xa.x, xa.y, xa.z, xa.w, xb.x, xb.y, xb.z, xb.w};
    ps += ((xf[0] + xf[1]) + (xf[2] + xf[3])) +
          ((xf[4] + xf[5]) + (xf[6] + xf[7]));
    __attribute__((aligned(16))) unsigned short s1[8], s3[8];
#pragma unroll
    for (int j = 0; j < 8; ++j) {
      unsigned short hh, mm, ll;
      split3(xf[j], hh, mm, ll);
      s1[j] = qlt2 ? hh : mm;
      s3[j] = qlt2 ? hh : ll;
    }
    bf16x8 a1 = *(bf16x8*)s1;
    bf16x8 a3 = *(bf16x8*)s3;
#pragma unroll
    for (int hh = 0; hh < 8; ++hh) {
      size_t b0 = (((size_t)(dg * 8 + hh) * 3) * 16 + n16) * 16 + oct * 8;
      bf16x8 b1 = *(const bf16x8*)(wfrag + b0 + p1 * 256);
      bf16x8 b2 = *(const bf16x8*)(wfrag + b0 + p2 * 256);
      bf16x8 b3 = *(const bf16x8*)(wfrag + b0 + p3 * 256);
      acc[hh] = __builtin_amdgcn_mfma_f32_16x16x32_bf16(a1, b1, acc[hh], 0, 0, 0);
      acc[hh] = __builtin_amdgcn_mfma_f32_16x16x32_bf16(a1, b2, acc[hh], 0, 0, 0);
      acc[hh] = __builtin_amdgcn_mfma_f32_16x16x32_bf16(a3, b3, acc[hh], 0, 0, 0);
    }
  }

  // wave-pair reduce: waves 4-7 dump, waves 0-3 add partner's partial.
  if (w >= 4) {
#pragma unroll
    for (int hh = 0; hh < 8; ++hh)
#pragma unroll
      for (int r = 0; r < 4; ++r) sAcc[w - 4][lane][hh * 4 + r] = acc[hh][r];
  }
  if (q < 2) sPs[w][q][n16] = ps;
  __syncthreads();
  if (w < 4) {
#pragma unroll
    for (int hh = 0; hh < 8; ++hh)
#pragma unroll
      for (int r = 0; r < 4; ++r)
        sAcc[w][lane][hh * 4 + r] = acc[hh][r] + sAcc[w][lane][hh * 4 + r];
  }
  if (t < 16) {
    float s = 0.f;
#pragma unroll
    for (int w2 = 0; w2 < 8; ++w2) s += sPs[w2][0][t] + sPs[w2][1][t];
    sMu[t] = s * (1.0f / 1024.0f);
  }
  __syncthreads();

  // epilogue: thread (head = t>>6, l = t&63) handles 4 acc regs.
  const int l = t & 63, head = t >> 6;
  const int lq = l >> 4, ln = l & 15;
  const float cs = csum[head * 16 + ln];
#pragma unroll
  for (int r = 0; r < 4; ++r) {
    const int f = head * 4 + r;
    float v = ((sAcc[0][l][f] + sAcc[1][l][f]) +
               (sAcc[2][l][f] + sAcc[3][l][f]));
    const int row16 = lq * 4 + r;
    float tv = v - sMu[row16] * cs;
    unsigned short vh, vm, vl;
    split3(tv, vh, vm, vl);
    size_t base = ((size_t)head * 8192 + r0 + row16) * 16 + ln;
    ph[base] = vh; pm[base] = vm; pl[base] = vl;
  }
}

// ---------------- K4: MFMA argmax partials (LDS-staged codebook) ------------
// Grid (32 rowgroups, 8 heads, 8 code-eighths) x 256 = 2048 blocks (8/CU).
// Per block: the (h,z) cfrag chunk (24KB contiguous) staged once into LDS.
// Wave = 64 rows (4 row-tiles, A-frags in regs). Per-lane codes ascend ->
// strict '>' = first max; shfl_xor(w16) lexicographic; merged in k_amred.
__global__ __launch_bounds__(256) void k_argmax(
    const unsigned short* __restrict__ ph, const unsigned short* __restrict__ pm,
    const unsigned short* __restrict__ pl, const unsigned short* __restrict__ cfrag,
    float* __restrict__ amv, int* __restrict__ ami) {
  __shared__ __align__(16) unsigned short sB[12288];   // 24 KB
  const int t = threadIdx.x;
  const int lane = t & 63, w = t >> 6;
  const int h = blockIdx.y;
  const int z = blockIdx.z;
  const int r0 = blockIdx.x * 256 + w * 64;
  const int q = lane >> 4, n16 = lane & 15;
  const int ehalf = (q & 1) * 8;
  const bool qlt2 = (q < 2);
  const int p1 = qlt2 ? 0 : 1, p2 = qlt2 ? 1 : 0, p3 = qlt2 ? 2 : 0;

  const float* src = (const float*)(cfrag + ((size_t)(h * 128 + z * 16) * 3) * 256);
#pragma unroll
  for (int i = 0; i < 6; ++i)
    stage16(src + ((size_t)((i * 4 + w) * 64) + lane) * 4,
            (float*)sB + (i * 4 + w) * 256);

  const unsigned short* pa1 = qlt2 ? ph : pm;   // A1 = [h|m]
  const unsigned short* pa3 = qlt2 ? ph : pl;   // A3 = [h|l]
  bf16x8 a1[4], a3[4];
#pragma unroll
  for (int rt = 0; rt < 4; ++rt) {
    size_t off = ((size_t)h * 8192 + r0 + rt * 16 + n16) * 16 + ehalf;
    a1[rt] = *(const bf16x8*)(pa1 + off);
    a3[rt] = *(const bf16x8*)(pa3 + off);
  }

  float best[4][4];
  int   bidx[4][4];
#pragma unroll
  for (int rt = 0; rt < 4; ++rt)
#pragma unroll
    for (int r = 0; r < 4; ++r) { best[rt][r] = -3.402823466e38f; bidx[rt][r] = 0; }

  __syncthreads();

  for (int tile = 0; tile < 16; ++tile) {
    const int b0 = tile * 768 + n16 * 16 + ehalf;
    bf16x8 b1 = *(const bf16x8*)(sB + b0 + p1 * 256);
    bf16x8 b2 = *(const bf16x8*)(sB + b0 + p2 * 256);
    bf16x8 b3 = *(const bf16x8*)(sB + b0 + p3 * 256);
    const int code = z * 256 + tile * 16 + n16;
#pragma unroll
    for (int rt = 0; rt < 4; ++rt) {
      f32x4 acc = {0.f, 0.f, 0.f, 0.f};
      acc = __builtin_amdgcn_mfma_f32_16x16x32_bf16(a1[rt], b1, acc, 0, 0, 0);
      acc = __builtin_amdgcn_mfma_f32_16x16x32_bf16(a1[rt], b2, acc, 0, 0, 0);
      acc = __builtin_amdgcn_mfma_f32_16x16x32_bf16(a3[rt], b3, acc, 0, 0, 0);
#pragma unroll
      for (int r = 0; r < 4; ++r)
        if (acc[r] > best[rt][r]) { best[rt][r] = acc[r]; bidx[rt][r] = code; }
    }
  }

#pragma unroll
  for (int off = 8; off >= 1; off >>= 1) {
#pragma unroll
    for (int rt = 0; rt < 4; ++rt)
#pragma unroll
      for (int r = 0; r < 4; ++r) {
        float ov = __shfl_xor(best[rt][r], off, 16);
        int   oi = __shfl_xor(bidx[rt][r], off, 16);
        if (ov > best[rt][r] || (ov == best[rt][r] && oi < bidx[rt][r])) {
          best[rt][r] = ov; bidx[rt][r] = oi;
        }
      }
  }
  if (n16 == 0) {
#pragma unroll
    for (int rt = 0; rt < 4; ++rt)
#pragma unroll
      for (int r = 0; r < 4; ++r) {
        int row = r0 + rt * 16 + q * 4 + r;
        size_t o = (size_t)z * 65536 + (size_t)row * 8 + h;
        amv[o] = best[rt][r]; ami[o] = bidx[rt][r];
      }
  }
}

// ---------------- K5: merge the eight code-eighths --------------------------
__global__ __launch_bounds__(256) void k_amred(const float* __restrict__ amv,
                                               const int* __restrict__ ami,
                                               int* __restrict__ out) {
  int i = blockIdx.x * 256 + threadIdx.x;   // 65536
  float bv = amv[i]; int bi = ami[i];
#pragma unroll
  for (int z = 1; z < 8; ++z) {
    float v = amv[(size_t)z * 65536 + i];
    if (v > bv) { bv = v; bi = ami[(size_t)z * 65536 + i]; }
  }
  out[i] = bi;
}

extern "C" void kernel_launch(void* const* d_in, const int* in_sizes, int n_in,
                              void* d_out, int out_size, void* d_ws, size_t ws_size,
                              hipStream_t stream) {
  (void)in_sizes; (void)n_in; (void)out_size; (void)ws_size;
  const float* x  = (const float*)d_in[0];   // [4,2048,1024]
  const float* rp = (const float*)d_in[1];   // [8,1024,16]
  const float* cb = (const float*)d_in[2];   // [8,2048,16]
  int* out = (int*)d_out;                    // [8192,8] int32

  float* ws = (float*)d_ws;
  float*          csum  = ws;                              // 128
  float*          amv   = ws + 128;                        // 524288
  int*            ami   = (int*)(ws + 524416);             // 524288
  unsigned short* wfrag = (unsigned short*)(ws + 1048704); // 393216 sh
  unsigned short* cfrag = (unsigned short*)(ws + 1245312); // 786432 sh
  unsigned short* ph    = (unsigned short*)(ws + 1638528); // 1048576 sh each
  unsigned short* pm    = (unsigned short*)(ws + 2162816);
  unsigned short* pl    = (unsigned short*)(ws + 2687104); // end ~12.8 MB

  hipLaunchKernelGGL(k_prep,    dim3(136),       dim3(256), 0, stream, cb, rp, cfrag, csum, wfrag);
  hipLaunchKernelGGL(k_proj,    dim3(512),       dim3(512), 0, stream, x, wfrag, csum, ph, pm, pl);
  hipLaunchKernelGGL(k_argmax,  dim3(32, 8, 8),  dim3(256), 0, stream, ph, pm, pl, cfrag, amv, ami);
  hipLaunchKernelGGL(k_amred,   dim3(256),       dim3(256), 0, stream, amv, ami, out);
}